// Round 13
// baseline (4096.978 us; speedup 1.0000x reference)
//
#include <hip/hip_runtime.h>

#define NP   16384
#define KNN  32
#define HDIM 128
#define ODIM 64

// ---------------- squared norms ----------------
template<int D>
__global__ __launch_bounds__(256)
void sq_kernel(const float* __restrict__ X, float* __restrict__ sq) {
    const int lane = threadIdx.x & 63;
    const int row  = blockIdx.x * 4 + (threadIdx.x >> 6);
    float s = 0.f;
    #pragma unroll
    for (int d = lane; d < D; d += 64) {
        const float v = X[(size_t)row * D + d];
        s = fmaf(v, v, s);
    }
    #pragma unroll
    for (int off = 32; off; off >>= 1) s += __shfl_down(s, off);
    if (lane == 0) sq[row] = s;
}

// ---------------- top-32 neighbors (streaming, sorted register top-k) -------
// score_j = dot(x_i,x_j) - 0.5*sq_j (argmax score == argmin d2 per row).
// TI=32 rows/block, JC=256 cols/tile (4 cols/lane: {lane+64h}), 8 waves,
// R=4 rows/wave, grid=512. Pure-DS inner loop (xi broadcast from LDS, xj
// per-lane b64): per pg = 96 LDS-cyc vs 128 VALU-cyc -> VALU-ratio > LDS.
// Top-32 SORTED (value desc, index asc on ties) in lanes 0..31.
template<int D>
__global__ __launch_bounds__(512)
void topk_kernel(const float* __restrict__ X, const float* __restrict__ sq,
                 int* __restrict__ topIdx) {
    constexpr int TI = 32, JC = 256;
    constexpr int R  = TI / 8;               // rows per wave = 4
    constexpr int NT = NP / JC;              // 64 tiles
    constexpr int NSTG = JC * D / 4 / 512;   // float4/thread per j-tile (16/8)
    __shared__ float2 xjP[(D / 2) * JC];     // [pair p][j]
    __shared__ float  xi_s[TI * D];          // [i][d] row-major (broadcast reads)

    const int t = threadIdx.x;
    const int lane = t & 63;
    const int waveU = __builtin_amdgcn_readfirstlane(t >> 6);   // SGPR wave id
    const int rowBase = blockIdx.x * TI;
    const float INF = __builtin_inff();

    // sorted top-32 per row: lane l<32 holds rank-l entry (desc value)
    float tv[R]; int tidx[R]; float minv[R];
    #pragma unroll
    for (int r = 0; r < R; ++r) { tv[r] = -INF; tidx[r] = 0x7fffffff; minv[r] = -INF; }

    // stage xi (row-major; consecutive lanes -> consecutive 16B)
    #pragma unroll
    for (int e4 = t; e4 < TI * D / 4; e4 += 512) {
        const float4 v = reinterpret_cast<const float4*>(X + (size_t)rowBase * D)[e4];
        *reinterpret_cast<float4*>(&xi_s[4 * e4]) = v;
    }

    float4 stg[NSTG];
    auto loadTile = [&](int jb) {
        #pragma unroll
        for (int s = 0; s < NSTG; ++s) {
            const int e = s * 512 + t;
            const int j = e & (JC - 1), dg = e >> 8;
            stg[s] = *reinterpret_cast<const float4*>(X + (size_t)(jb + j) * D + 4 * dg);
        }
    };
    auto writeTile = [&]() {
        #pragma unroll
        for (int s = 0; s < NSTG; ++s) {
            const int e = s * 512 + t;
            const int j = e & (JC - 1), dg = e >> 8;
            xjP[(2 * dg + 0) * JC + j] = make_float2(stg[s].x, stg[s].y);
            xjP[(2 * dg + 1) * JC + j] = make_float2(stg[s].z, stg[s].w);
        }
    };

    loadTile(0);
    writeTile();
    __syncthreads();
    loadTile(JC);                             // prefetch tile 1 into regs

    for (int it = 0; it < NT; ++it) {
        const int jb = it * JC;
        float sub[4];
        #pragma unroll
        for (int h = 0; h < 4; ++h)
            sub[h] = 0.5f * sq[jb + 64 * h + lane];     // hidden under GEMM

        float acc[R][4];
        #pragma unroll
        for (int r = 0; r < R; ++r)
            #pragma unroll
            for (int h = 0; h < 4; ++h) acc[r][h] = 0.f;

        #pragma unroll 2
        for (int pg = 0; pg < D / 4; ++pg) {            // 4 d's per iter
            float4 a[R];
            #pragma unroll
            for (int r = 0; r < R; ++r)                 // wave-uniform -> broadcast
                a[r] = *reinterpret_cast<const float4*>(
                    &xi_s[(waveU * R + r) * D + 4 * pg]);
            float2 b0[4], b1[4];
            #pragma unroll
            for (int h = 0; h < 4; ++h) {
                b0[h] = xjP[(2 * pg + 0) * JC + 64 * h + lane];
                b1[h] = xjP[(2 * pg + 1) * JC + 64 * h + lane];
            }
            #pragma unroll
            for (int r = 0; r < R; ++r)
                #pragma unroll
                for (int h = 0; h < 4; ++h) {           // d-ascending (numerics)
                    acc[r][h] = fmaf(a[r].x, b0[h].x, acc[r][h]);
                    acc[r][h] = fmaf(a[r].y, b0[h].y, acc[r][h]);
                    acc[r][h] = fmaf(a[r].z, b1[h].x, acc[r][h]);
                    acc[r][h] = fmaf(a[r].w, b1[h].y, acc[r][h]);
                }
        }
        __syncthreads();                   // all waves done reading xjP
        if (it + 1 < NT) writeTile();
        __syncthreads();                   // next tile staged
        if (it + 2 < NT) loadTile(jb + 2 * JC);

        // scan: h ascending (64-j blocks), ctz ascending within -> stable ties
        #pragma unroll
        for (int h = 0; h < 4; ++h) {
            float sv[R];
            unsigned long long m[R];
            #pragma unroll
            for (int r = 0; r < R; ++r) {
                sv[r] = acc[r][h] - sub[h];
                m[r] = __ballot(sv[r] > minv[r]);
            }
            while (m[0] | m[1] | m[2] | m[3]) {
                #pragma unroll
                for (int r = 0; r < R; ++r) {
                    if (m[r]) {
                        const int l = __builtin_ctzll(m[r]);
                        m[r] &= m[r] - 1;
                        const float cv = __shfl(sv[r], l);
                        const int   cj = jb + 64 * h + l;
                        const float upv = __shfl_up(tv[r], 1);   // hoisted off chain
                        const int   upi = __shfl_up(tidx[r], 1);
                        const bool ge = (lane < KNN) && (tv[r] >= cv);
                        const int p = __popcll(__ballot(ge));    // ==32 -> no-op
                        if (lane == p)                   { tv[r] = cv;  tidx[r] = cj; }
                        else if (lane > p && lane < KNN) { tv[r] = upv; tidx[r] = upi; }
                    }
                }
            }
        }
        #pragma unroll
        for (int r = 0; r < R; ++r)
            minv[r] = __shfl(tv[r], KNN - 1);   // exact refresh, once per tile
    }

    if (lane < KNN) {
        #pragma unroll
        for (int r = 0; r < R; ++r)
            topIdx[(size_t)(rowBase + waveU * R + r) * KNN + lane] = tidx[r];
    }
}

// ---------------- gather + MLP + pool + out ----------------
// h_k = A@nbr_k + B@x; pooled = mean_k clip(h_k); out = [pooled, x] @ W2^T.
// Wave -> (row, k-group); neighbor rows via uniform s_load (no LDS gather).
// Lane -> hh pair {2l, 2l+1}: A/B weights as float2 LDS reads (2-way = free).
template<int D, int LAYER>
__global__ __launch_bounds__(512)
void mlp_kernel(const float* __restrict__ X, const int* __restrict__ topIdx,
                const float* __restrict__ W, const float* __restrict__ W2,
                float* __restrict__ out) {
    constexpr int RPB = 2, WPR = 4, KPT = 8;   // 8 waves = RPB rows x WPR k-groups
    constexpr int W2C  = HDIM + D;
    constexpr int SPL2 = 512 / (RPB * ODIM);   // 4
    constexpr int CL   = W2C / SPL2;
    __shared__ float AT[D * HDIM];             // [d][hh]: B^T first, then A^T
    __shared__ float xi[RPB][D];
    __shared__ float part[RPB][WPR][HDIM];

    const int t = threadIdx.x;
    const int lane = t & 63;
    const int waveU = __builtin_amdgcn_readfirstlane(t >> 6);
    const int rowBase = blockIdx.x * RPB;
    const int row = waveU / WPR;
    const int wkb = waveU % WPR;
    const int hh2 = 2 * lane;                  // lane's hh pair

    // phase 0: stage xi and B^T
    if (t < RPB * D / 4) {
        const int i = t / (D / 4), dg = t % (D / 4);
        const float4 v = *reinterpret_cast<const float4*>(
            X + (size_t)(rowBase + i) * D + 4 * dg);
        xi[i][4 * dg + 0] = v.x; xi[i][4 * dg + 1] = v.y;
        xi[i][4 * dg + 2] = v.z; xi[i][4 * dg + 3] = v.w;
    }
    for (int e = t; e < HDIM * D / 4; e += 512) {
        const int hh = e % HDIM, dg = e / HDIM;
        const float4 v = *reinterpret_cast<const float4*>(
            W + (size_t)hh * (2 * D) + D + 4 * dg);          // B = W[:, D:2D]
        AT[(4 * dg + 0) * HDIM + hh] = v.x; AT[(4 * dg + 1) * HDIM + hh] = v.y;
        AT[(4 * dg + 2) * HDIM + hh] = v.z; AT[(4 * dg + 3) * HDIM + hh] = v.w;
    }
    __syncthreads();

    // phase 1: hself (lane's 2 hh) in registers
    float hs0 = 0.f, hs1 = 0.f;
    #pragma unroll 8
    for (int d = 0; d < D; ++d) {
        const float a = xi[row][d];            // broadcast LDS read
        const float2 b = *reinterpret_cast<const float2*>(&AT[d * HDIM + hh2]);
        hs0 = fmaf(b.x, a, hs0);
        hs1 = fmaf(b.y, a, hs1);
    }
    __syncthreads();                           // done reading AT-as-B^T

    // phase 1b: restage A^T
    for (int e = t; e < HDIM * D / 4; e += 512) {
        const int hh = e % HDIM, dg = e / HDIM;
        const float4 v = *reinterpret_cast<const float4*>(
            W + (size_t)hh * (2 * D) + 4 * dg);              // A = W[:, 0:D]
        AT[(4 * dg + 0) * HDIM + hh] = v.x; AT[(4 * dg + 1) * HDIM + hh] = v.y;
        AT[(4 * dg + 2) * HDIM + hh] = v.z; AT[(4 * dg + 3) * HDIM + hh] = v.w;
    }
    __syncthreads();

    // phase 2: GEMM; B-operand (neighbor rows) via uniform s_load
    const int* __restrict__ tIdx = topIdx + (size_t)(rowBase + row) * KNN + wkb * KPT;
    const float* nrow[KPT];
    #pragma unroll
    for (int r = 0; r < KPT; ++r)
        nrow[r] = X + (size_t)tIdx[r] * D;

    float acc0[KPT], acc1[KPT];
    #pragma unroll
    for (int r = 0; r < KPT; ++r) { acc0[r] = 0.f; acc1[r] = 0.f; }

    for (int dg = 0; dg < D / 4; ++dg) {
        float4 b[KPT];
        #pragma unroll
        for (int r = 0; r < KPT; ++r)          // uniform -> s_load_dwordx4
            b[r] = *reinterpret_cast<const float4*>(nrow[r] + 4 * dg);
        const float2 a0 = *reinterpret_cast<const float2*>(&AT[(4 * dg + 0) * HDIM + hh2]);
        const float2 a1 = *reinterpret_cast<const float2*>(&AT[(4 * dg + 1) * HDIM + hh2]);
        const float2 a2 = *reinterpret_cast<const float2*>(&AT[(4 * dg + 2) * HDIM + hh2]);
        const float2 a3 = *reinterpret_cast<const float2*>(&AT[(4 * dg + 3) * HDIM + hh2]);
        #pragma unroll
        for (int r = 0; r < KPT; ++r) {        // d-ascending accumulation
            acc0[r] = fmaf(a0.x, b[r].x, acc0[r]); acc1[r] = fmaf(a0.y, b[r].x, acc1[r]);
            acc0[r] = fmaf(a1.x, b[r].y, acc0[r]); acc1[r] = fmaf(a1.y, b[r].y, acc1[r]);
            acc0[r] = fmaf(a2.x, b[r].z, acc0[r]); acc1[r] = fmaf(a2.y, b[r].z, acc1[r]);
            acc0[r] = fmaf(a3.x, b[r].w, acc0[r]); acc1[r] = fmaf(a3.y, b[r].w, acc1[r]);
        }
    }

    // pooling partials (clip then sum over this wave's KPT neighbors)
    float p0 = 0.f, p1 = 0.f;
    #pragma unroll
    for (int r = 0; r < KPT; ++r) {
        p0 += fminf(1.f, fmaxf(-1.f, acc0[r] + hs0));
        p1 += fminf(1.f, fmaxf(-1.f, acc1[r] + hs1));
    }
    *reinterpret_cast<float2*>(&part[row][wkb][hh2]) =
        make_float2(p0 * (1.f / KNN), p1 * (1.f / KNN));
    __syncthreads();

    // phase 3: out = [pooled, x] @ W2^T, split over SPL2 column chunks
    {
        const int og   = t / SPL2;
        const int spl  = t % SPL2;
        const int orow = og >> 6, o = og & 63;
        const int c0   = spl * CL;
        float s = 0.f;
        for (int c = c0; c < c0 + CL; ++c) {
            float vsrc;
            if (c < HDIM) {
                vsrc = part[orow][0][c] + part[orow][1][c]
                     + part[orow][2][c] + part[orow][3][c];
            } else {
                vsrc = xi[orow][c - HDIM];
            }
            s = fmaf(vsrc, W2[(size_t)o * W2C + c], s);
        }
        #pragma unroll
        for (int off = SPL2 / 2; off; off >>= 1) s += __shfl_down(s, off);
        if (spl == 0) {
            if (LAYER == 0)
                out[(size_t)(rowBase + orow) * 128 + 64 + o] = s;  // x1 cols 64..127
            else
                out[(size_t)(rowBase + orow) * ODIM + o] = s;      // final output
        }
    }
    if (LAYER == 0 && t < RPB * 64) {
        const int orow = t >> 6, d = t & 63;
        out[(size_t)(rowBase + orow) * 128 + d] = xi[orow][d];     // x1 cols 0..63
    }
}

extern "C" void kernel_launch(void* const* d_in, const int* in_sizes, int n_in,
                              void* d_out, int out_size, void* d_ws, size_t ws_size,
                              hipStream_t stream) {
    const float* x    = (const float*)d_in[0];
    const float* w0   = (const float*)d_in[1];
    const float* w2_0 = (const float*)d_in[2];
    const float* w1   = (const float*)d_in[3];
    const float* w2_1 = (const float*)d_in[4];
    float* out = (float*)d_out;

    char* ws = (char*)d_ws;
    float* sq  = (float*)ws;                                     // NP floats
    int*   idx = (int*)(ws + (size_t)NP * 4);                    // NP*32 ints
    float* x1  = (float*)(ws + (size_t)NP * 4 + (size_t)NP * KNN * 4);  // NP*128

    // layer 0 (D = 64)
    sq_kernel<64><<<NP / 4, 256, 0, stream>>>(x, sq);
    topk_kernel<64><<<NP / 32, 512, 0, stream>>>(x, sq, idx);
    mlp_kernel<64, 0><<<NP / 2, 512, 0, stream>>>(x, idx, w0, w2_0, x1);

    // layer 1 (D = 128, x1 = [x, o0])
    sq_kernel<128><<<NP / 4, 256, 0, stream>>>(x1, sq);
    topk_kernel<128><<<NP / 32, 512, 0, stream>>>(x1, sq, idx);
    mlp_kernel<128, 1><<<NP / 2, 512, 0, stream>>>(x1, idx, w1, w2_1, out);
}

// Round 14
// 2482.764 us; speedup vs baseline: 1.6502x; 1.6502x over previous
//
#include <hip/hip_runtime.h>
#include <hip/hip_bf16.h>

#define NP   16384
#define KNN  32
#define HDIM 128
#define ODIM 64

typedef __attribute__((ext_vector_type(8))) short bf16x8;
typedef __attribute__((ext_vector_type(4))) float f32x4;

// ---------------- split fp32 -> bf16 (hi, lo) planes ----------------
__global__ __launch_bounds__(256)
void split_kernel(const float* __restrict__ X, unsigned short* __restrict__ hi,
                  unsigned short* __restrict__ lo, int n4) {
    const int i = blockIdx.x * 256 + threadIdx.x;
    if (i >= n4) return;
    const float4 v = reinterpret_cast<const float4*>(X)[i];
    const float vv[4] = {v.x, v.y, v.z, v.w};
    ushort4 h, l;
    unsigned short* hp = &h.x;
    unsigned short* lp = &l.x;
    #pragma unroll
    for (int c = 0; c < 4; ++c) {
        __hip_bfloat16 hb = __float2bfloat16(vv[c]);           // RNE
        const float hf = __bfloat162float(hb);
        __hip_bfloat16 lb = __float2bfloat16(vv[c] - hf);
        hp[c] = *reinterpret_cast<unsigned short*>(&hb);
        lp[c] = *reinterpret_cast<unsigned short*>(&lb);
    }
    reinterpret_cast<ushort4*>(hi)[i] = h;
    reinterpret_cast<ushort4*>(lo)[i] = l;
}

// ---------------- squared norms (fp32, exact as before) ----------------
template<int D>
__global__ __launch_bounds__(256)
void sq_kernel(const float* __restrict__ X, float* __restrict__ sq) {
    const int lane = threadIdx.x & 63;
    const int row  = blockIdx.x * 4 + (threadIdx.x >> 6);
    float s = 0.f;
    #pragma unroll
    for (int d = lane; d < D; d += 64) {
        const float v = X[(size_t)row * D + d];
        s = fmaf(v, v, s);
    }
    #pragma unroll
    for (int off = 32; off; off >>= 1) s += __shfl_down(s, off);
    if (lane == 0) sq[row] = s;
}

// ---------------- top-32 neighbors: MFMA scores + sorted register top-k ----
// score = hi.hi + hi.lo + lo.hi (bf16 split, fp32 accum) - 0.5*sq_j.
// TI=32 rows/block, JC=128 cols/tile, 8 waves; wave w computes cols
// [16w,16w+16) via mfma_f32_16x16x32_bf16 (A = xi rows, frags resident in
// VGPRs all kernel; B = xj cols from XOR-swizzled bf16 LDS planes).
// C layout (m89): col=lane&15, row=(lane>>4)*4+reg -> scatter to
// scoresT[col][row] (stride 33), barrier, then the R11 sorted-insert scan
// (wave owns rows [4*wave,4*wave+4), lane owns cols {lane, lane+64}).
template<int D>
__global__ __launch_bounds__(512)
void topk_kernel(const unsigned short* __restrict__ Xhi,
                 const unsigned short* __restrict__ Xlo,
                 const float* __restrict__ sq, int* __restrict__ topIdx) {
    constexpr int TI = 32, JC = 128, SS = TI + 1;
    constexpr int NT = NP / JC;
    constexpr int KQ = D / 8;           // 16B k-groups per row
    constexpr int KS = D / 32;          // MFMA k-steps
    constexpr int NS = JC * KQ / 512;   // 16B slots per plane per thread
    constexpr int PL = JC * KQ;         // slots per plane
    __shared__ __align__(16) unsigned short xjB[2 * PL * 8];  // hi plane, lo plane
    __shared__ float scoresT[JC * SS];

    const int t = threadIdx.x;
    const int lane = t & 63;
    const int waveU = __builtin_amdgcn_readfirstlane(t >> 6);
    const int rowBase = blockIdx.x * TI;
    const int l15 = lane & 15, l4 = lane >> 4;
    const float INF = __builtin_inff();

    // A fragments (32 xi rows), resident in registers for the whole kernel.
    // A[row=l15][k = 32*s + 8*l4 + e]
    bf16x8 Ahi[2][KS], Alo[2][KS];
    #pragma unroll
    for (int rb = 0; rb < 2; ++rb)
        #pragma unroll
        for (int s = 0; s < KS; ++s) {
            const size_t off = (size_t)(rowBase + 16 * rb + l15) * D + 32 * s + 8 * l4;
            Ahi[rb][s] = *reinterpret_cast<const bf16x8*>(Xhi + off);
            Alo[rb][s] = *reinterpret_cast<const bf16x8*>(Xlo + off);
        }

    float tv[4]; int tidx[4]; float minv[4];
    #pragma unroll
    for (int r = 0; r < 4; ++r) { tv[r] = -INF; tidx[r] = 0x7fffffff; minv[r] = -INF; }

    bf16x8 stgH[NS], stgL[NS];
    auto loadTile = [&](int jb) {
        #pragma unroll
        for (int s = 0; s < NS; ++s) {
            const int id = s * 512 + t;
            const int j = id / KQ, kq = id % KQ;
            const size_t off = (size_t)(jb + j) * D + 8 * kq;
            stgH[s] = *reinterpret_cast<const bf16x8*>(Xhi + off);
            stgL[s] = *reinterpret_cast<const bf16x8*>(Xlo + off);
        }
    };
    auto writeTile = [&]() {
        #pragma unroll
        for (int s = 0; s < NS; ++s) {
            const int id = s * 512 + t;
            const int j = id / KQ, kq = id % KQ;
            const int slot = j * KQ + (kq ^ (j & (KQ - 1)));   // bank-quad swizzle
            *reinterpret_cast<bf16x8*>(&xjB[(size_t)slot * 8]) = stgH[s];
            *reinterpret_cast<bf16x8*>(&xjB[(size_t)(PL + slot) * 8]) = stgL[s];
        }
    };

    loadTile(0);
    writeTile();
    loadTile(JC);
    __syncthreads();

    for (int it = 0; it < NT; ++it) {
        const int jb = it * JC;
        const float sub0 = 0.5f * sq[jb + lane];
        const float sub1 = 0.5f * sq[jb + 64 + lane];

        // MFMA: this wave's 16 cols x 32 rows
        f32x4 C0 = {0.f, 0.f, 0.f, 0.f}, C1 = {0.f, 0.f, 0.f, 0.f};
        const int jcol = 16 * waveU + l15;
        #pragma unroll
        for (int s = 0; s < KS; ++s) {
            const int kq = 4 * s + l4;
            const int slot = jcol * KQ + (kq ^ (jcol & (KQ - 1)));
            const bf16x8 Bh = *reinterpret_cast<const bf16x8*>(&xjB[(size_t)slot * 8]);
            const bf16x8 Bl = *reinterpret_cast<const bf16x8*>(&xjB[(size_t)(PL + slot) * 8]);
            C0 = __builtin_amdgcn_mfma_f32_16x16x32_bf16(Ahi[0][s], Bh, C0, 0, 0, 0);
            C1 = __builtin_amdgcn_mfma_f32_16x16x32_bf16(Ahi[1][s], Bh, C1, 0, 0, 0);
            C0 = __builtin_amdgcn_mfma_f32_16x16x32_bf16(Ahi[0][s], Bl, C0, 0, 0, 0);
            C1 = __builtin_amdgcn_mfma_f32_16x16x32_bf16(Ahi[1][s], Bl, C1, 0, 0, 0);
            C0 = __builtin_amdgcn_mfma_f32_16x16x32_bf16(Alo[0][s], Bh, C0, 0, 0, 0);
            C1 = __builtin_amdgcn_mfma_f32_16x16x32_bf16(Alo[1][s], Bh, C1, 0, 0, 0);
        }
        // scatter C -> scoresT[col][row]
        #pragma unroll
        for (int r = 0; r < 4; ++r) {
            scoresT[jcol * SS + (4 * l4 + r)]      = C0[r];
            scoresT[jcol * SS + (16 + 4 * l4 + r)] = C1[r];
        }
        __syncthreads();                 // B1: xjB reads + score writes done

        if (it + 1 < NT) writeTile();    // stage next tile (overlaps scan)
        if (it + 2 < NT) loadTile(jb + 2 * JC);

        // scan: R11 sorted-insert; wave owns local rows [4*waveU, 4*waveU+4)
        #pragma unroll
        for (int h = 0; h < 2; ++h) {
            float sv[4];
            unsigned long long m[4];
            #pragma unroll
            for (int r = 0; r < 4; ++r) {
                sv[r] = scoresT[(h * 64 + lane) * SS + (waveU * 4 + r)]
                      - (h ? sub1 : sub0);
                m[r] = __ballot(sv[r] > minv[r]);
            }
            while (m[0] | m[1] | m[2] | m[3]) {
                #pragma unroll
                for (int r = 0; r < 4; ++r) {
                    if (m[r]) {
                        const int l = __builtin_ctzll(m[r]);  // ascending j => stable
                        m[r] &= m[r] - 1;
                        const float cv = __shfl(sv[r], l);
                        const int   cj = jb + h * 64 + l;
                        const float upv = __shfl_up(tv[r], 1);   // hoisted off chain
                        const int   upi = __shfl_up(tidx[r], 1);
                        const bool ge = (lane < KNN) && (tv[r] >= cv);
                        const int p = __popcll(__ballot(ge));    // ==32 -> no-op
                        if (lane == p)                   { tv[r] = cv;  tidx[r] = cj; }
                        else if (lane > p && lane < KNN) { tv[r] = upv; tidx[r] = upi; }
                    }
                }
            }
        }
        #pragma unroll
        for (int r = 0; r < 4; ++r)
            minv[r] = __shfl(tv[r], KNN - 1);   // exact refresh, once per tile

        __syncthreads();                 // B2: staging writes + scan reads done
    }

    if (lane < KNN) {
        #pragma unroll
        for (int r = 0; r < 4; ++r)
            topIdx[(size_t)(rowBase + waveU * 4 + r) * KNN + lane] = tidx[r];
    }
}

// ---------------- gather + MLP + pool + out (unchanged) ----------------
template<int D, int LAYER>
__global__ __launch_bounds__(512)
void mlp_kernel(const float* __restrict__ X, const int* __restrict__ topIdx,
                const float* __restrict__ W, const float* __restrict__ W2,
                float* __restrict__ out) {
    constexpr int RPB = 2, WPR = 4, KPT = 8;
    constexpr int W2C  = HDIM + D;
    constexpr int SPL2 = 512 / (RPB * ODIM);   // 4
    constexpr int CL   = W2C / SPL2;
    __shared__ float AT[D * HDIM];             // [d][hh]: B^T first, then A^T
    __shared__ float xi[RPB][D];
    __shared__ float part[RPB][WPR][HDIM];

    const int t = threadIdx.x;
    const int lane = t & 63;
    const int waveU = __builtin_amdgcn_readfirstlane(t >> 6);
    const int rowBase = blockIdx.x * RPB;
    const int row = waveU / WPR;
    const int wkb = waveU % WPR;
    const int hh2 = 2 * lane;

    if (t < RPB * D / 4) {
        const int i = t / (D / 4), dg = t % (D / 4);
        const float4 v = *reinterpret_cast<const float4*>(
            X + (size_t)(rowBase + i) * D + 4 * dg);
        xi[i][4 * dg + 0] = v.x; xi[i][4 * dg + 1] = v.y;
        xi[i][4 * dg + 2] = v.z; xi[i][4 * dg + 3] = v.w;
    }
    for (int e = t; e < HDIM * D / 4; e += 512) {
        const int hh = e % HDIM, dg = e / HDIM;
        const float4 v = *reinterpret_cast<const float4*>(
            W + (size_t)hh * (2 * D) + D + 4 * dg);          // B = W[:, D:2D]
        AT[(4 * dg + 0) * HDIM + hh] = v.x; AT[(4 * dg + 1) * HDIM + hh] = v.y;
        AT[(4 * dg + 2) * HDIM + hh] = v.z; AT[(4 * dg + 3) * HDIM + hh] = v.w;
    }
    __syncthreads();

    float hs0 = 0.f, hs1 = 0.f;
    #pragma unroll 8
    for (int d = 0; d < D; ++d) {
        const float a = xi[row][d];
        const float2 b = *reinterpret_cast<const float2*>(&AT[d * HDIM + hh2]);
        hs0 = fmaf(b.x, a, hs0);
        hs1 = fmaf(b.y, a, hs1);
    }
    __syncthreads();

    for (int e = t; e < HDIM * D / 4; e += 512) {
        const int hh = e % HDIM, dg = e / HDIM;
        const float4 v = *reinterpret_cast<const float4*>(
            W + (size_t)hh * (2 * D) + 4 * dg);              // A = W[:, 0:D]
        AT[(4 * dg + 0) * HDIM + hh] = v.x; AT[(4 * dg + 1) * HDIM + hh] = v.y;
        AT[(4 * dg + 2) * HDIM + hh] = v.z; AT[(4 * dg + 3) * HDIM + hh] = v.w;
    }
    __syncthreads();

    const int* __restrict__ tIdx = topIdx + (size_t)(rowBase + row) * KNN + wkb * KPT;
    const float* nrow[KPT];
    #pragma unroll
    for (int r = 0; r < KPT; ++r)
        nrow[r] = X + (size_t)tIdx[r] * D;

    float acc0[KPT], acc1[KPT];
    #pragma unroll
    for (int r = 0; r < KPT; ++r) { acc0[r] = 0.f; acc1[r] = 0.f; }

    for (int dg = 0; dg < D / 4; ++dg) {
        float4 b[KPT];
        #pragma unroll
        for (int r = 0; r < KPT; ++r)
            b[r] = *reinterpret_cast<const float4*>(nrow[r] + 4 * dg);
        const float2 a0 = *reinterpret_cast<const float2*>(&AT[(4 * dg + 0) * HDIM + hh2]);
        const float2 a1 = *reinterpret_cast<const float2*>(&AT[(4 * dg + 1) * HDIM + hh2]);
        const float2 a2 = *reinterpret_cast<const float2*>(&AT[(4 * dg + 2) * HDIM + hh2]);
        const float2 a3 = *reinterpret_cast<const float2*>(&AT[(4 * dg + 3) * HDIM + hh2]);
        #pragma unroll
        for (int r = 0; r < KPT; ++r) {
            acc0[r] = fmaf(a0.x, b[r].x, acc0[r]); acc1[r] = fmaf(a0.y, b[r].x, acc1[r]);
            acc0[r] = fmaf(a1.x, b[r].y, acc0[r]); acc1[r] = fmaf(a1.y, b[r].y, acc1[r]);
            acc0[r] = fmaf(a2.x, b[r].z, acc0[r]); acc1[r] = fmaf(a2.y, b[r].z, acc1[r]);
            acc0[r] = fmaf(a3.x, b[r].w, acc0[r]); acc1[r] = fmaf(a3.y, b[r].w, acc1[r]);
        }
    }

    float p0 = 0.f, p1 = 0.f;
    #pragma unroll
    for (int r = 0; r < KPT; ++r) {
        p0 += fminf(1.f, fmaxf(-1.f, acc0[r] + hs0));
        p1 += fminf(1.f, fmaxf(-1.f, acc1[r] + hs1));
    }
    *reinterpret_cast<float2*>(&part[row][wkb][hh2]) =
        make_float2(p0 * (1.f / KNN), p1 * (1.f / KNN));
    __syncthreads();

    {
        const int og   = t / SPL2;
        const int spl  = t % SPL2;
        const int orow = og >> 6, o = og & 63;
        const int c0   = spl * CL;
        float s = 0.f;
        for (int c = c0; c < c0 + CL; ++c) {
            float vsrc;
            if (c < HDIM) {
                vsrc = part[orow][0][c] + part[orow][1][c]
                     + part[orow][2][c] + part[orow][3][c];
            } else {
                vsrc = xi[orow][c - HDIM];
            }
            s = fmaf(vsrc, W2[(size_t)o * W2C + c], s);
        }
        #pragma unroll
        for (int off = SPL2 / 2; off; off >>= 1) s += __shfl_down(s, off);
        if (spl == 0) {
            if (LAYER == 0)
                out[(size_t)(rowBase + orow) * 128 + 64 + o] = s;
            else
                out[(size_t)(rowBase + orow) * ODIM + o] = s;
        }
    }
    if (LAYER == 0 && t < RPB * 64) {
        const int orow = t >> 6, d = t & 63;
        out[(size_t)(rowBase + orow) * 128 + d] = xi[orow][d];
    }
}

extern "C" void kernel_launch(void* const* d_in, const int* in_sizes, int n_in,
                              void* d_out, int out_size, void* d_ws, size_t ws_size,
                              hipStream_t stream) {
    const float* x    = (const float*)d_in[0];
    const float* w0   = (const float*)d_in[1];
    const float* w2_0 = (const float*)d_in[2];
    const float* w1   = (const float*)d_in[3];
    const float* w2_1 = (const float*)d_in[4];
    float* out = (float*)d_out;

    char* ws = (char*)d_ws;
    float* sq  = (float*)ws;                                          // 64 KB
    int*   idx = (int*)(ws + (size_t)NP * 4);                         // 2 MB
    float* x1  = (float*)(ws + (size_t)NP * 4 + (size_t)NP * KNN * 4);  // 8 MB
    unsigned short* xhi = (unsigned short*)(ws + (size_t)NP * 4
                          + (size_t)NP * KNN * 4 + (size_t)NP * HDIM * 4);  // 4 MB
    unsigned short* xlo = xhi + (size_t)NP * HDIM;                    // 4 MB

    // layer 0 (D = 64)
    split_kernel<<<NP * 64 / 4 / 256, 256, 0, stream>>>(x, xhi, xlo, NP * 64 / 4);
    sq_kernel<64><<<NP / 4, 256, 0, stream>>>(x, sq);
    topk_kernel<64><<<NP / 32, 512, 0, stream>>>(xhi, xlo, sq, idx);
    mlp_kernel<64, 0><<<NP / 2, 512, 0, stream>>>(x, idx, w0, w2_0, x1);

    // layer 1 (D = 128, x1 = [x, o0])
    split_kernel<<<NP * 128 / 4 / 256, 256, 0, stream>>>(x1, xhi, xlo, NP * 128 / 4);
    sq_kernel<128><<<NP / 4, 256, 0, stream>>>(x1, sq);
    topk_kernel<128><<<NP / 32, 512, 0, stream>>>(xhi, xlo, sq, idx);
    mlp_kernel<128, 1><<<NP / 2, 512, 0, stream>>>(x1, idx, w1, w2_1, out);
}

// Round 15
// 2482.516 us; speedup vs baseline: 1.6503x; 1.0001x over previous
//
#include <hip/hip_runtime.h>
#include <hip/hip_bf16.h>

#define NP   16384
#define KNN  32
#define HDIM 128
#define ODIM 64

typedef __attribute__((ext_vector_type(8))) short bf16x8;
typedef __attribute__((ext_vector_type(4))) float f32x4;

// ---------------- split fp32 -> bf16 (hi, lo) planes ----------------
__global__ __launch_bounds__(256)
void split_kernel(const float* __restrict__ X, unsigned short* __restrict__ hi,
                  unsigned short* __restrict__ lo, int n4) {
    const int i = blockIdx.x * 256 + threadIdx.x;
    if (i >= n4) return;
    const float4 v = reinterpret_cast<const float4*>(X)[i];
    const float vv[4] = {v.x, v.y, v.z, v.w};
    ushort4 h, l;
    unsigned short* hp = &h.x;
    unsigned short* lp = &l.x;
    #pragma unroll
    for (int c = 0; c < 4; ++c) {
        __hip_bfloat16 hb = __float2bfloat16(vv[c]);           // RNE
        const float hf = __bfloat162float(hb);
        __hip_bfloat16 lb = __float2bfloat16(vv[c] - hf);
        hp[c] = *reinterpret_cast<unsigned short*>(&hb);
        lp[c] = *reinterpret_cast<unsigned short*>(&lb);
    }
    reinterpret_cast<ushort4*>(hi)[i] = h;
    reinterpret_cast<ushort4*>(lo)[i] = l;
}

// ---------------- squared norms (fp32, exact as before) ----------------
template<int D>
__global__ __launch_bounds__(256)
void sq_kernel(const float* __restrict__ X, float* __restrict__ sq) {
    const int lane = threadIdx.x & 63;
    const int row  = blockIdx.x * 4 + (threadIdx.x >> 6);
    float s = 0.f;
    #pragma unroll
    for (int d = lane; d < D; d += 64) {
        const float v = X[(size_t)row * D + d];
        s = fmaf(v, v, s);
    }
    #pragma unroll
    for (int off = 32; off; off >>= 1) s += __shfl_down(s, off);
    if (lane == 0) sq[row] = s;
}

// ---------------- top-32 neighbors: MFMA scores + sorted register top-k ----
// score = hi.hi + hi.lo + lo.hi (bf16 split, fp32 accum) - 0.5*sq_j.
// TI=32 rows/block, JC=128 cols/tile, 8 waves; wave w computes cols
// [16w,16w+16) via mfma_f32_16x16x32_bf16.  3 accumulators per row-block
// (chain depth 4, not 12).  LDS = 64K (xjB) + 16K (scoresR, unpadded
// [TI][JC]) = 81920 B exactly -> 2 blocks/CU.
// C layout (m89): col=lane&15, row=(lane>>4)*4+reg -> scoresR[row][col];
// scan reads are lane-consecutive (conflict-free); scatter 4-way (accepted).
template<int D>
__global__ __launch_bounds__(512)
void topk_kernel(const unsigned short* __restrict__ Xhi,
                 const unsigned short* __restrict__ Xlo,
                 const float* __restrict__ sq, int* __restrict__ topIdx) {
    constexpr int TI = 32, JC = 128;
    constexpr int NT = NP / JC;
    constexpr int KQ = D / 8;           // 16B k-groups per row
    constexpr int KS = D / 32;          // MFMA k-steps
    constexpr int NS = JC * KQ / 512;   // 16B slots per plane per thread
    constexpr int PL = JC * KQ;         // slots per plane
    __shared__ __align__(16) unsigned short xjB[2 * PL * 8];  // hi plane, lo plane
    __shared__ float scoresR[TI * JC];  // [row][col], unpadded

    const int t = threadIdx.x;
    const int lane = t & 63;
    const int waveU = __builtin_amdgcn_readfirstlane(t >> 6);
    const int rowBase = blockIdx.x * TI;
    const int l15 = lane & 15, l4 = lane >> 4;
    const float INF = __builtin_inff();

    // A fragments (32 xi rows), resident in registers for the whole kernel.
    bf16x8 Ahi[2][KS], Alo[2][KS];
    #pragma unroll
    for (int rb = 0; rb < 2; ++rb)
        #pragma unroll
        for (int s = 0; s < KS; ++s) {
            const size_t off = (size_t)(rowBase + 16 * rb + l15) * D + 32 * s + 8 * l4;
            Ahi[rb][s] = *reinterpret_cast<const bf16x8*>(Xhi + off);
            Alo[rb][s] = *reinterpret_cast<const bf16x8*>(Xlo + off);
        }

    float tv[4]; int tidx[4]; float minv[4];
    #pragma unroll
    for (int r = 0; r < 4; ++r) { tv[r] = -INF; tidx[r] = 0x7fffffff; minv[r] = -INF; }

    bf16x8 stgH[NS], stgL[NS];
    auto loadTile = [&](int jb) {
        #pragma unroll
        for (int s = 0; s < NS; ++s) {
            const int id = s * 512 + t;
            const int j = id / KQ, kq = id % KQ;
            const size_t off = (size_t)(jb + j) * D + 8 * kq;
            stgH[s] = *reinterpret_cast<const bf16x8*>(Xhi + off);
            stgL[s] = *reinterpret_cast<const bf16x8*>(Xlo + off);
        }
    };
    auto writeTile = [&]() {
        #pragma unroll
        for (int s = 0; s < NS; ++s) {
            const int id = s * 512 + t;
            const int j = id / KQ, kq = id % KQ;
            const int slot = j * KQ + (kq ^ (j & (KQ - 1)));   // bank-quad swizzle
            *reinterpret_cast<bf16x8*>(&xjB[(size_t)slot * 8]) = stgH[s];
            *reinterpret_cast<bf16x8*>(&xjB[(size_t)(PL + slot) * 8]) = stgL[s];
        }
    };

    loadTile(0);
    writeTile();
    loadTile(JC);
    __syncthreads();

    for (int it = 0; it < NT; ++it) {
        const int jb = it * JC;
        const float sub0 = 0.5f * sq[jb + lane];
        const float sub1 = 0.5f * sq[jb + 64 + lane];

        // MFMA: this wave's 16 cols x 32 rows; 3 independent chains per block
        f32x4 Ca0 = {0,0,0,0}, Cb0 = {0,0,0,0}, Cc0 = {0,0,0,0};
        f32x4 Ca1 = {0,0,0,0}, Cb1 = {0,0,0,0}, Cc1 = {0,0,0,0};
        const int jcol = 16 * waveU + l15;
        #pragma unroll
        for (int s = 0; s < KS; ++s) {
            const int kq = 4 * s + l4;
            const int slot = jcol * KQ + (kq ^ (jcol & (KQ - 1)));
            const bf16x8 Bh = *reinterpret_cast<const bf16x8*>(&xjB[(size_t)slot * 8]);
            const bf16x8 Bl = *reinterpret_cast<const bf16x8*>(&xjB[(size_t)(PL + slot) * 8]);
            Ca0 = __builtin_amdgcn_mfma_f32_16x16x32_bf16(Ahi[0][s], Bh, Ca0, 0, 0, 0);
            Ca1 = __builtin_amdgcn_mfma_f32_16x16x32_bf16(Ahi[1][s], Bh, Ca1, 0, 0, 0);
            Cb0 = __builtin_amdgcn_mfma_f32_16x16x32_bf16(Ahi[0][s], Bl, Cb0, 0, 0, 0);
            Cb1 = __builtin_amdgcn_mfma_f32_16x16x32_bf16(Ahi[1][s], Bl, Cb1, 0, 0, 0);
            Cc0 = __builtin_amdgcn_mfma_f32_16x16x32_bf16(Alo[0][s], Bh, Cc0, 0, 0, 0);
            Cc1 = __builtin_amdgcn_mfma_f32_16x16x32_bf16(Alo[1][s], Bh, Cc1, 0, 0, 0);
        }
        // scatter C -> scoresR[row][col]  (4-way bank conflict, 8 stores: cheap)
        #pragma unroll
        for (int r = 0; r < 4; ++r) {
            scoresR[(4 * l4 + r) * JC + jcol]        = (Ca0[r] + Cb0[r]) + Cc0[r];
            scoresR[(16 + 4 * l4 + r) * JC + jcol]   = (Ca1[r] + Cb1[r]) + Cc1[r];
        }
        __syncthreads();                 // B1: xjB reads + score writes done

        if (it + 1 < NT) writeTile();    // stage next tile (overlaps scan)
        if (it + 2 < NT) loadTile(jb + 2 * JC);

        // scan: sorted-insert; wave owns rows [4*waveU, 4*waveU+4)
        #pragma unroll
        for (int h = 0; h < 2; ++h) {
            float sv[4];
            unsigned long long m[4];
            #pragma unroll
            for (int r = 0; r < 4; ++r) {
                sv[r] = scoresR[(waveU * 4 + r) * JC + h * 64 + lane]
                      - (h ? sub1 : sub0);
                m[r] = __ballot(sv[r] > minv[r]);
            }
            while (m[0] | m[1] | m[2] | m[3]) {
                #pragma unroll
                for (int r = 0; r < 4; ++r) {
                    if (m[r]) {
                        const int l = __builtin_ctzll(m[r]);  // ascending j => stable
                        m[r] &= m[r] - 1;
                        const float cv = __shfl(sv[r], l);
                        const int   cj = jb + h * 64 + l;
                        const float upv = __shfl_up(tv[r], 1);   // hoisted off chain
                        const int   upi = __shfl_up(tidx[r], 1);
                        const bool ge = (lane < KNN) && (tv[r] >= cv);
                        const int p = __popcll(__ballot(ge));    // ==32 -> no-op
                        if (lane == p)                   { tv[r] = cv;  tidx[r] = cj; }
                        else if (lane > p && lane < KNN) { tv[r] = upv; tidx[r] = upi; }
                    }
                }
            }
        }
        #pragma unroll
        for (int r = 0; r < 4; ++r)
            minv[r] = __shfl(tv[r], KNN - 1);   // exact refresh, once per tile

        __syncthreads();                 // B2: staging writes + scan reads done
    }

    if (lane < KNN) {
        #pragma unroll
        for (int r = 0; r < 4; ++r)
            topIdx[(size_t)(rowBase + waveU * 4 + r) * KNN + lane] = tidx[r];
    }
}

// ---------------- gather + MLP + pool + out (unchanged) ----------------
template<int D, int LAYER>
__global__ __launch_bounds__(512)
void mlp_kernel(const float* __restrict__ X, const int* __restrict__ topIdx,
                const float* __restrict__ W, const float* __restrict__ W2,
                float* __restrict__ out) {
    constexpr int RPB = 2, WPR = 4, KPT = 8;
    constexpr int W2C  = HDIM + D;
    constexpr int SPL2 = 512 / (RPB * ODIM);   // 4
    constexpr int CL   = W2C / SPL2;
    __shared__ float AT[D * HDIM];             // [d][hh]: B^T first, then A^T
    __shared__ float xi[RPB][D];
    __shared__ float part[RPB][WPR][HDIM];

    const int t = threadIdx.x;
    const int lane = t & 63;
    const int waveU = __builtin_amdgcn_readfirstlane(t >> 6);
    const int rowBase = blockIdx.x * RPB;
    const int row = waveU / WPR;
    const int wkb = waveU % WPR;
    const int hh2 = 2 * lane;

    if (t < RPB * D / 4) {
        const int i = t / (D / 4), dg = t % (D / 4);
        const float4 v = *reinterpret_cast<const float4*>(
            X + (size_t)(rowBase + i) * D + 4 * dg);
        xi[i][4 * dg + 0] = v.x; xi[i][4 * dg + 1] = v.y;
        xi[i][4 * dg + 2] = v.z; xi[i][4 * dg + 3] = v.w;
    }
    for (int e = t; e < HDIM * D / 4; e += 512) {
        const int hh = e % HDIM, dg = e / HDIM;
        const float4 v = *reinterpret_cast<const float4*>(
            W + (size_t)hh * (2 * D) + D + 4 * dg);          // B = W[:, D:2D]
        AT[(4 * dg + 0) * HDIM + hh] = v.x; AT[(4 * dg + 1) * HDIM + hh] = v.y;
        AT[(4 * dg + 2) * HDIM + hh] = v.z; AT[(4 * dg + 3) * HDIM + hh] = v.w;
    }
    __syncthreads();

    float hs0 = 0.f, hs1 = 0.f;
    #pragma unroll 8
    for (int d = 0; d < D; ++d) {
        const float a = xi[row][d];
        const float2 b = *reinterpret_cast<const float2*>(&AT[d * HDIM + hh2]);
        hs0 = fmaf(b.x, a, hs0);
        hs1 = fmaf(b.y, a, hs1);
    }
    __syncthreads();

    for (int e = t; e < HDIM * D / 4; e += 512) {
        const int hh = e % HDIM, dg = e / HDIM;
        const float4 v = *reinterpret_cast<const float4*>(
            W + (size_t)hh * (2 * D) + 4 * dg);              // A = W[:, 0:D]
        AT[(4 * dg + 0) * HDIM + hh] = v.x; AT[(4 * dg + 1) * HDIM + hh] = v.y;
        AT[(4 * dg + 2) * HDIM + hh] = v.z; AT[(4 * dg + 3) * HDIM + hh] = v.w;
    }
    __syncthreads();

    const int* __restrict__ tIdx = topIdx + (size_t)(rowBase + row) * KNN + wkb * KPT;
    const float* nrow[KPT];
    #pragma unroll
    for (int r = 0; r < KPT; ++r)
        nrow[r] = X + (size_t)tIdx[r] * D;

    float acc0[KPT], acc1[KPT];
    #pragma unroll
    for (int r = 0; r < KPT; ++r) { acc0[r] = 0.f; acc1[r] = 0.f; }

    for (int dg = 0; dg < D / 4; ++dg) {
        float4 b[KPT];
        #pragma unroll
        for (int r = 0; r < KPT; ++r)
            b[r] = *reinterpret_cast<const float4*>(nrow[r] + 4 * dg);
        const float2 a0 = *reinterpret_cast<const float2*>(&AT[(4 * dg + 0) * HDIM + hh2]);
        const float2 a1 = *reinterpret_cast<const float2*>(&AT[(4 * dg + 1) * HDIM + hh2]);
        const float2 a2 = *reinterpret_cast<const float2*>(&AT[(4 * dg + 2) * HDIM + hh2]);
        const float2 a3 = *reinterpret_cast<const float2*>(&AT[(4 * dg + 3) * HDIM + hh2]);
        #pragma unroll
        for (int r = 0; r < KPT; ++r) {
            acc0[r] = fmaf(a0.x, b[r].x, acc0[r]); acc1[r] = fmaf(a0.y, b[r].x, acc1[r]);
            acc0[r] = fmaf(a1.x, b[r].y, acc0[r]); acc1[r] = fmaf(a1.y, b[r].y, acc1[r]);
            acc0[r] = fmaf(a2.x, b[r].z, acc0[r]); acc1[r] = fmaf(a2.y, b[r].z, acc1[r]);
            acc0[r] = fmaf(a3.x, b[r].w, acc0[r]); acc1[r] = fmaf(a3.y, b[r].w, acc1[r]);
        }
    }

    float p0 = 0.f, p1 = 0.f;
    #pragma unroll
    for (int r = 0; r < KPT; ++r) {
        p0 += fminf(1.f, fmaxf(-1.f, acc0[r] + hs0));
        p1 += fminf(1.f, fmaxf(-1.f, acc1[r] + hs1));
    }
    *reinterpret_cast<float2*>(&part[row][wkb][hh2]) =
        make_float2(p0 * (1.f / KNN), p1 * (1.f / KNN));
    __syncthreads();

    {
        const int og   = t / SPL2;
        const int spl  = t % SPL2;
        const int orow = og >> 6, o = og & 63;
        const int c0   = spl * CL;
        float s = 0.f;
        for (int c = c0; c < c0 + CL; ++c) {
            float vsrc;
            if (c < HDIM) {
                vsrc = part[orow][0][c] + part[orow][1][c]
                     + part[orow][2][c] + part[orow][3][c];
            } else {
                vsrc = xi[orow][c - HDIM];
            }
            s = fmaf(vsrc, W2[(size_t)o * W2C + c], s);
        }
        #pragma unroll
        for (int off = SPL2 / 2; off; off >>= 1) s += __shfl_down(s, off);
        if (spl == 0) {
            if (LAYER == 0)
                out[(size_t)(rowBase + orow) * 128 + 64 + o] = s;
            else
                out[(size_t)(rowBase + orow) * ODIM + o] = s;
        }
    }
    if (LAYER == 0 && t < RPB * 64) {
        const int orow = t >> 6, d = t & 63;
        out[(size_t)(rowBase + orow) * 128 + d] = xi[orow][d];
    }
}

extern "C" void kernel_launch(void* const* d_in, const int* in_sizes, int n_in,
                              void* d_out, int out_size, void* d_ws, size_t ws_size,
                              hipStream_t stream) {
    const float* x    = (const float*)d_in[0];
    const float* w0   = (const float*)d_in[1];
    const float* w2_0 = (const float*)d_in[2];
    const float* w1   = (const float*)d_in[3];
    const float* w2_1 = (const float*)d_in[4];
    float* out = (float*)d_out;

    char* ws = (char*)d_ws;
    float* sq  = (float*)ws;                                          // 64 KB
    int*   idx = (int*)(ws + (size_t)NP * 4);                         // 2 MB
    float* x1  = (float*)(ws + (size_t)NP * 4 + (size_t)NP * KNN * 4);  // 8 MB
    unsigned short* xhi = (unsigned short*)(ws + (size_t)NP * 4
                          + (size_t)NP * KNN * 4 + (size_t)NP * HDIM * 4);  // 4 MB
    unsigned short* xlo = xhi + (size_t)NP * HDIM;                    // 4 MB

    // layer 0 (D = 64)
    split_kernel<<<NP * 64 / 4 / 256, 256, 0, stream>>>(x, xhi, xlo, NP * 64 / 4);
    sq_kernel<64><<<NP / 4, 256, 0, stream>>>(x, sq);
    topk_kernel<64><<<NP / 32, 512, 0, stream>>>(xhi, xlo, sq, idx);
    mlp_kernel<64, 0><<<NP / 2, 512, 0, stream>>>(x, idx, w0, w2_0, x1);

    // layer 1 (D = 128, x1 = [x, o0])
    split_kernel<<<NP * 128 / 4 / 256, 256, 0, stream>>>(x1, xhi, xlo, NP * 128 / 4);
    sq_kernel<128><<<NP / 4, 256, 0, stream>>>(x1, sq);
    topk_kernel<128><<<NP / 32, 512, 0, stream>>>(xhi, xlo, sq, idx);
    mlp_kernel<128, 1><<<NP / 2, 512, 0, stream>>>(x1, idx, w1, w2_1, out);
}